// Round 1
// baseline (263.130 us; speedup 1.0000x reference)
//
#include <hip/hip_runtime.h>
#include <hip/hip_bf16.h>
#include <math.h>

// Problem constants (from setup_inputs)
#define BB 8
#define QN 512
#define SN 64
#define TN 128
#define DD 128
#define STAT_K 8
#define TOK_K 16
#define SCALE 0.08838834764831845f   // 1/sqrt(128)
#define NEGBIG -1e6f

typedef float f4 __attribute__((ext_vector_type(4)));

// ---------------------------------------------------------------------------
// Generic projection GEMM: C[M,128] = A[M,128] @ W[128,128], fp32.
// BM = 128 rows/block, 256 threads, 8x8 per-thread tile.
// transposeBlk != 0: output stored per-128-row-block transposed: C[blk][col][row%128]
// (used for k_tok so the token kernel reads lane-per-token coalesced).
// ---------------------------------------------------------------------------
__global__ __launch_bounds__(256) void proj_gemm(const float* __restrict__ A,
                                                 const float* __restrict__ W,
                                                 float* __restrict__ C,
                                                 int transposeBlk)
{
    __shared__ float As[128 * 128];   // 64 KB, k-swizzled
    __shared__ float Ws[128 * 128];   // 64 KB
    const int tid = threadIdx.x;
    const size_t rowBase = (size_t)blockIdx.x * 128;

    // Stage A (swizzled) and W. 4096 float4 slots each, 16 per thread.
    #pragma unroll
    for (int i = 0; i < 16; ++i) {
        int idx = i * 256 + tid;          // 0..4095
        int row = idx >> 5;               // 0..127
        int c4  = idx & 31;               // float4 column index
        f4 av = ((const f4*)(A + (rowBase + row) * 128))[c4];
        int kcol = (c4 * 4) ^ (((row >> 3) & 3) << 2);   // XOR swizzle (bank-conflict-free reads)
        *(f4*)&As[row * 128 + kcol] = av;
        f4 wv = ((const f4*)(W + (size_t)row * 128))[c4];
        *(f4*)&Ws[row * 128 + c4 * 4] = wv;
    }
    __syncthreads();

    const int tx = tid & 15;    // column group: cols tx*4..tx*4+3 and 64+tx*4..+3
    const int ty = tid >> 4;    // row group: rows ty*8..ty*8+7

    float acc[8][8];
    #pragma unroll
    for (int i = 0; i < 8; ++i)
        #pragma unroll
        for (int j = 0; j < 8; ++j) acc[i][j] = 0.f;

    #pragma unroll 2
    for (int k0 = 0; k0 < 128; k0 += 4) {
        f4 wl[4], wh[4];
        #pragma unroll
        for (int kk = 0; kk < 4; ++kk) {
            wl[kk] = *(const f4*)&Ws[(k0 + kk) * 128 + tx * 4];
            wh[kk] = *(const f4*)&Ws[(k0 + kk) * 128 + 64 + tx * 4];
        }
        #pragma unroll
        for (int i = 0; i < 8; ++i) {
            const int r = ty * 8 + i;
            f4 a = *(const f4*)&As[r * 128 + (k0 ^ (((r >> 3) & 3) << 2))];
            #pragma unroll
            for (int kk = 0; kk < 4; ++kk) {
                #pragma unroll
                for (int j = 0; j < 4; ++j) {
                    acc[i][j]     = fmaf(a[kk], wl[kk][j], acc[i][j]);
                    acc[i][4 + j] = fmaf(a[kk], wh[kk][j], acc[i][4 + j]);
                }
            }
        }
    }

    if (!transposeBlk) {
        #pragma unroll
        for (int i = 0; i < 8; ++i) {
            size_t row = rowBase + ty * 8 + i;
            f4 lo = {acc[i][0], acc[i][1], acc[i][2], acc[i][3]};
            f4 hi = {acc[i][4], acc[i][5], acc[i][6], acc[i][7]};
            *(f4*)&C[row * 128 + tx * 4]      = lo;
            *(f4*)&C[row * 128 + 64 + tx * 4] = hi;
        }
    } else {
        float* Cb = C + ((size_t)blockIdx.x << 14);   // blk * 128*128
        #pragma unroll
        for (int j = 0; j < 4; ++j) {
            int clo = tx * 4 + j;
            int chi = 64 + tx * 4 + j;
            f4 v0 = {acc[0][j], acc[1][j], acc[2][j], acc[3][j]};
            f4 v1 = {acc[4][j], acc[5][j], acc[6][j], acc[7][j]};
            *(f4*)&Cb[clo * 128 + ty * 8]     = v0;
            *(f4*)&Cb[clo * 128 + ty * 8 + 4] = v1;
            f4 v2 = {acc[0][4 + j], acc[1][4 + j], acc[2][4 + j], acc[3][4 + j]};
            f4 v3 = {acc[4][4 + j], acc[5][4 + j], acc[6][4 + j], acc[7][4 + j]};
            *(f4*)&Cb[chi * 128 + ty * 8]     = v2;
            *(f4*)&Cb[chi * 128 + ty * 8 + 4] = v3;
        }
    }
}

// ---------------------------------------------------------------------------
// Stat level: scores = q_stat . k_stat^T * scale, mask invalid, top-8,
// softmax over the kept 8 (others are exactly 0 after exp underflow).
// One wave per (b,q). Lane = stat index s (SN == 64 == wave size).
// ---------------------------------------------------------------------------
__global__ __launch_bounds__(64, 4) void stat_topk(const float* __restrict__ qs,
                                                   const float* __restrict__ ks,
                                                   const int* __restrict__ vlen,
                                                   int* __restrict__ sel_i,
                                                   float* __restrict__ sel_w)
{
    const int bq   = blockIdx.x;       // b*QN + q
    const int b    = bq >> 9;
    const int lane = threadIdx.x;      // stat index s

    const f4* q4 = (const f4*)(qs + (size_t)bq * 128);
    const f4* k4 = (const f4*)(ks + (size_t)(b * SN + lane) * 128);
    float acc = 0.f;
    #pragma unroll 8
    for (int kk = 0; kk < 32; ++kk) {
        f4 q = q4[kk];
        f4 k = k4[kk];
        acc = fmaf(q[0], k[0], acc);
        acc = fmaf(q[1], k[1], acc);
        acc = fmaf(q[2], k[2], acc);
        acc = fmaf(q[3], k[3], acc);
    }
    float score = acc * SCALE;
    if (lane >= vlen[b]) score = NEGBIG;

    float work = score;
    float tv[STAT_K];
    int   ti[STAT_K];
    #pragma unroll
    for (int j = 0; j < STAT_K; ++j) {
        float m = work;
        #pragma unroll
        for (int off = 32; off > 0; off >>= 1) m = fmaxf(m, __shfl_xor(m, off));
        unsigned long long ball = __ballot(work == m);
        int L = __ffsll(ball) - 1;     // lowest index wins ties (matches jax top_k)
        tv[j] = m;
        ti[j] = L;
        if (lane == L) work = -3.4e38f;
    }

    // softmax over the 8 kept entries; -1e6 entries give exp()==0 exactly
    float w[STAT_K];
    float Z = 0.f;
    #pragma unroll
    for (int j = 0; j < STAT_K; ++j) { w[j] = expf(tv[j] - tv[0]); Z += w[j]; }
    float invZ = 1.f / Z;

    if (lane < STAT_K) {
        sel_i[(size_t)bq * STAT_K + lane] = ti[lane];
        sel_w[(size_t)bq * STAT_K + lane] = w[lane] * invZ;
    }
}

// ---------------------------------------------------------------------------
// Token level + PV: one wave per (b,q). For each of the 8 selected stats:
// scores over 128 tokens (lane owns tokens lane and lane+64, k_tokT is
// [b*s][d][t] so reads are coalesced), top-16, softmax, gather-accumulate
// 16 v rows scaled by stat_w * tok_w. Output accumulated in registers.
// ---------------------------------------------------------------------------
__global__ __launch_bounds__(64, 4) void tok_pv(const float* __restrict__ qt,
                                                const float* __restrict__ kT,
                                                const float* __restrict__ v,
                                                const int* __restrict__ sel_i,
                                                const float* __restrict__ sel_w,
                                                float* __restrict__ outp)
{
    const int blk  = blockIdx.x;
    const int b    = blk & 7;           // XCD affinity: batch b per XCD slot
    const int q    = blk >> 3;
    const int bq   = b * QN + q;
    const int lane = threadIdx.x;

    __shared__ float qsh[128];
    qsh[lane]      = qt[(size_t)bq * 128 + lane];
    qsh[lane + 64] = qt[(size_t)bq * 128 + 64 + lane];
    __syncthreads();

    float o0 = 0.f, o1 = 0.f;   // output dims lane, lane+64

    for (int si = 0; si < STAT_K; ++si) {
        int   s  = sel_i[(size_t)bq * STAT_K + si];
        float sw = sel_w[(size_t)bq * STAT_K + si];
        if (sw == 0.f) continue;   // exactly-zero stat weight: contribution is exactly 0

        const float* kb = kT + ((size_t)(b * SN + s) << 14);
        float a0 = 0.f, a1 = 0.f;
        #pragma unroll 8
        for (int d = 0; d < 128; ++d) {
            float qv = qsh[d];
            a0 = fmaf(qv, kb[d * 128 + lane], a0);
            a1 = fmaf(qv, kb[d * 128 + 64 + lane], a1);
        }
        a0 *= SCALE;
        a1 *= SCALE;

        // top-16 of 128 (2 candidates per lane), jax tie-break = lowest token idx
        float w0 = a0, w1 = a1;
        float tv[TOK_K];
        int   tt[TOK_K];
        #pragma unroll
        for (int j = 0; j < TOK_K; ++j) {
            float lm = fmaxf(w0, w1);
            float m = lm;
            #pragma unroll
            for (int off = 32; off > 0; off >>= 1) m = fmaxf(m, __shfl_xor(m, off));
            unsigned long long b0 = __ballot(w0 == m);
            int tj;
            if (b0) {
                int L = __ffsll(b0) - 1;
                tj = L;
                if (lane == L) w0 = -3.4e38f;
            } else {
                unsigned long long b1 = __ballot(w1 == m);
                int L = __ffsll(b1) - 1;
                tj = L + 64;
                if (lane == L) w1 = -3.4e38f;
            }
            tv[j] = m;
            tt[j] = tj;
        }

        float pw[TOK_K];
        float Z = 0.f;
        #pragma unroll
        for (int j = 0; j < TOK_K; ++j) { pw[j] = expf(tv[j] - tv[0]); Z += pw[j]; }
        float cscale = sw / Z;   // fold stat weight into combine weight

        const float* vb = v + ((size_t)(b * SN + s) << 14);
        #pragma unroll
        for (int j = 0; j < TOK_K; ++j) {
            float cw = pw[j] * cscale;
            o0 = fmaf(cw, vb[tt[j] * 128 + lane], o0);
            o1 = fmaf(cw, vb[tt[j] * 128 + 64 + lane], o1);
        }
    }

    outp[(size_t)bq * 128 + lane]      = o0;
    outp[(size_t)bq * 128 + 64 + lane] = o1;
}

// ---------------------------------------------------------------------------
extern "C" void kernel_launch(void* const* d_in, const int* in_sizes, int n_in,
                              void* d_out, int out_size, void* d_ws, size_t ws_size,
                              hipStream_t stream)
{
    const float* queries    = (const float*)d_in[0];
    const float* stat_keys  = (const float*)d_in[1];
    const float* token_keys = (const float*)d_in[2];
    const float* values     = (const float*)d_in[3];
    const int*   vlen       = (const int*)d_in[4];
    const float* Wq_stat    = (const float*)d_in[5];
    const float* Wq_token   = (const float*)d_in[6];
    const float* Wk_stat    = (const float*)d_in[7];
    const float* Wk_token   = (const float*)d_in[8];
    const float* Wv         = (const float*)d_in[9];
    const float* Wo         = (const float*)d_in[10];

    char* ws = (char*)d_ws;
    float* q_stat  = (float*)(ws);                 // 4096*128 f32 = 2 MB
    float* q_tok   = (float*)(ws + 2097152);       // 2 MB
    float* k_stat  = (float*)(ws + 4194304);       // 512*128 f32 = 256 KB
    float* k_tokT  = (float*)(ws + 4456448);       // [512][128d][128t] f32 = 32 MB
    float* v       = (float*)(ws + 38010880);      // 65536*128 f32 = 32 MB
    int*   sel_i   = (int*)  (ws + 71565312);      // 4096*8 = 128 KB
    float* sel_w   = (float*)(ws + 71696384);      // 128 KB
    float* out_pre = (float*)(ws + 71827456);      // 2 MB   (total 73,924,608 B)

    // Projections
    proj_gemm<<<32,  256, 0, stream>>>(queries,    Wq_stat,  q_stat, 0);
    proj_gemm<<<32,  256, 0, stream>>>(queries,    Wq_token, q_tok,  0);
    proj_gemm<<<4,   256, 0, stream>>>(stat_keys,  Wk_stat,  k_stat, 0);
    proj_gemm<<<512, 256, 0, stream>>>(token_keys, Wk_token, k_tokT, 1);  // transposed per (b,s)
    proj_gemm<<<512, 256, 0, stream>>>(values,     Wv,       v,      0);

    // Stat-level top-8 selection + weights
    stat_topk<<<BB * QN, 64, 0, stream>>>(q_stat, k_stat, vlen, sel_i, sel_w);

    // Token-level top-16 + PV accumulate (selected stats only)
    tok_pv<<<BB * QN, 64, 0, stream>>>(q_tok, k_tokT, v, sel_i, sel_w, out_pre);

    // Output projection
    proj_gemm<<<32, 256, 0, stream>>>(out_pre, Wo, (float*)d_out, 0);
}